// Round 8
// baseline (13903.000 us; speedup 1.0000x reference)
//
#include <hip/hip_runtime.h>

typedef unsigned int u32;

// sizes: B=16, L=256, D=256, H=256, E=256, V=172, T=128  (all f32)
// R8: ZERO-HOP redesign. grid 16 x 1024 threads; WG g owns batch g entirely.
// No cross-WG communication in the recurrence loop: per step everything (gates,
// LSTM, hW2, scores, softmax, ctx, o) is computed locally on one CU. Weights are
// streamed from L2 each step (W_ih_o+W_hh = 2MB/step, L2-resident, ~0.9us/XCD/step,
// hidden under ~2.4us of VALU issue by 16-wave TLP). Identities used:
//   ctx = (sum_l e_l img_l)/se  (from imgs input directly; no Pimg table)
//   o   = tanh(W3 @ [h; ctx])
// o-history kept in LDS (stride 260 words: 16B-aligned rows + conflict-free
// 8-lane-per-t epilogue reads); logits+softmax folded into the kernel epilogue
// (8 lanes per (t), shuffle-only reductions). No k_init, no k_logits.
// The only shared data is gtok (emb-part of gates): built 16-way split once, with
// the proven plain-stores + RELEASE-flag(wbl2) + relaxed-poll pattern. Flags use
// SIGNED compare: 0xAA poison is negative -> blocks; stale flag==1 on re-launch
// short-circuits safely (gtok values are input-deterministic, rewritten identical).

// workspace layout (bytes)
#define OFF_BAR  0ull          // u32 flag[16] at w*64B (one-time gtok sync)
#define OFF_GTOK 1024ull       // f32 [172][1024]  emb-part of gates + b_ih + b_hh
#define OFF_ENC  705536ull     // f32 [16][256][256]  per-batch enc_proj
// end = 705536 + 4194304 = 4,899,840 bytes

__device__ __forceinline__ float sigm(float x){ return 1.0f/(1.0f+__expf(-x)); }
__device__ __forceinline__ float tanh_f(float x){ return 1.0f - 2.0f/(1.0f+__expf(2.0f*x)); }

struct F8 { float v[8]; };
__device__ __forceinline__ F8 ld8f(const float* q){
  F8 r; float4 a = *(const float4*)q; float4 b = *(const float4*)(q+4);
  r.v[0]=a.x;r.v[1]=a.y;r.v[2]=a.z;r.v[3]=a.w;r.v[4]=b.x;r.v[5]=b.y;r.v[6]=b.z;r.v[7]=b.w;
  return r;
}
__device__ __forceinline__ float dot8(const F8& w, const float* x){
  float4 a = *(const float4*)x; float4 b = *(const float4*)(x+4);
  return w.v[0]*a.x + w.v[1]*a.y + w.v[2]*a.z + w.v[3]*a.w
       + w.v[4]*b.x + w.v[5]*b.y + w.v[6]*b.z + w.v[7]*b.w;
}

// ---------------- single kernel: recurrence + logits ----------------
extern "C" __global__ __launch_bounds__(1024, 1)
void k_all(const float* __restrict__ imgs, const int* __restrict__ tgt,
           const float* __restrict__ emb,  const float* __restrict__ W_ih,
           const float* __restrict__ W_hh, const float* __restrict__ b_ih,
           const float* __restrict__ b_hh, const float* __restrict__ W1,
           const float* __restrict__ W2,   const float* __restrict__ W3,
           const float* __restrict__ Wout, const float* __restrict__ beta,
           const float* __restrict__ whW,  const float* __restrict__ whb,
           const float* __restrict__ wcW,  const float* __restrict__ wcb,
           const float* __restrict__ woW,  const float* __restrict__ wob,
           char* __restrict__ ws, float* __restrict__ out)
{
  const int tid = threadIdx.x;
  const int g = blockIdx.x;

  u32*   flags = (u32*)(ws + OFF_BAR);
  float* gtok  = (float*)(ws + OFF_GTOK);
  float* ENCg  = (float*)(ws + OFF_ENC) + (size_t)g*65536;

  // LDS: 133120 + 4096 + 7*1024 + 128 = 144,512 B  (<160KB; 1 WG/CU)
  __shared__ __align__(16) float oLDS[128*260];   // o history, row stride 260 words
  __shared__ __align__(16) float sG[1024];        // gates staging / setup scratch
  __shared__ __align__(16) float sH[256];
  __shared__ __align__(16) float sC[256];
  __shared__ __align__(16) float sO[256];
  __shared__ __align__(16) float sHw2[256];       // also mean_enc during setup
  __shared__ __align__(16) float sE[256];
  __shared__ __align__(16) float sCtx[256];
  __shared__ __align__(16) float sBeta[256];
  __shared__ float sScal[32];

  if (tid < 256) sBeta[tid] = beta[tid];

  // ---- gtok share (tokens v = g mod 16): row j of [4H]: W_ih[j][0:256]@emb[v]+biases ----
  for (int v = g; v < 172; v += 16){
    __syncthreads();
    if (tid < 256) sG[tid] = emb[(size_t)v*256 + tid];
    __syncthreads();
    const float* wr = W_ih + (size_t)tid*512;
    float a = 0.f;
    #pragma unroll 8
    for (int c=0; c<32; c++) a += dot8(ld8f(wr + c*8), sG + c*8);
    gtok[(size_t)v*1024 + tid] = a + b_ih[tid] + b_hh[tid];   // plain; flushed by release
  }
  __syncthreads();                                  // all waves' gtok stores drained
  if (tid == 0)
    __hip_atomic_store(flags + g*16, 1u, __ATOMIC_RELEASE, __HIP_MEMORY_SCOPE_AGENT);

  // ---- ENC: enc[l][d] = W1[d] @ imgs[g][l], in 4 chunks of 64 rows (staged in oLDS) ----
  for (int ch=0; ch<4; ch++){
    { const float4* src = (const float4*)(imgs + ((size_t)g*256 + ch*64)*256);
      float4* dst = (float4*)oLDS;
      #pragma unroll
      for (int k=0; k<4; k++) dst[tid + k*1024] = src[tid + k*1024];
    }
    __syncthreads();
    { const int d = tid & 255, lq = tid >> 8;
      float acc[16];
      #pragma unroll
      for (int i=0; i<16; i++) acc[i]=0.f;
      const float* w1r = W1 + (size_t)d*256;
      for (int c=0; c<32; c++){
        F8 wv = ld8f(w1r + c*8);
        #pragma unroll
        for (int i=0; i<16; i++) acc[i] += dot8(wv, oLDS + (lq*16+i)*256 + c*8);
      }
      for (int i=0; i<16; i++) ENCg[(size_t)(ch*64 + lq*16 + i)*256 + d] = acc[i];
    }
    __syncthreads();
  }

  // ---- mean_enc -> sHw2 ----
  { const int d = tid & 255, lq = tid >> 8;
    float m = 0.f;
    for (int i=0; i<64; i++) m += imgs[((size_t)g*256 + lq*64 + i)*256 + d];
    sG[lq*256 + d] = m;
  }
  __syncthreads();
  if (tid < 256)
    sHw2[tid] = (sG[tid] + sG[256+tid] + sG[512+tid] + sG[768+tid]) * (1.0f/256.0f);
  __syncthreads();

  // ---- init states h0/c0/o0 (u = tid>>2, quarter q = tid&3; 4-lane shfl reduce) ----
  { const int u = tid >> 2, q = tid & 3;
    const float* x = sHw2 + q*64;
    float ah=0.f, ac=0.f, ao=0.f;
    #pragma unroll
    for (int c=0; c<8; c++){
      ah += dot8(ld8f(whW + (size_t)u*256 + q*64 + c*8), x + c*8);
      ac += dot8(ld8f(wcW + (size_t)u*256 + q*64 + c*8), x + c*8);
      ao += dot8(ld8f(woW + (size_t)u*256 + q*64 + c*8), x + c*8);
    }
    ah += __shfl_xor(ah,1); ah += __shfl_xor(ah,2);
    ac += __shfl_xor(ac,1); ac += __shfl_xor(ac,2);
    ao += __shfl_xor(ao,1); ao += __shfl_xor(ao,2);
    if (q == 0){
      sH[u] = tanhf(ah + whb[u]);
      sC[u] = tanhf(ac + wcb[u]);
      sO[u] = tanhf(ao + wob[u]);
    }
  }

  // ---- one-time wait: gtok ready (signed compare; poison is negative) ----
  if (tid < 16){
    const u32* f = flags + tid*16;
    while ((int)__hip_atomic_load(f, __ATOMIC_RELAXED, __HIP_MEMORY_SCOPE_AGENT) < 1)
      __builtin_amdgcn_s_sleep(1);
  }
  __syncthreads();

  // ---- recurrence loop: fully local, 7 barriers/step ----
  const int* tgt_g = tgt + g*128;
  const float* wio = W_ih + (size_t)tid*512 + 256;   // o-half of own gate row
  const float* whh = W_hh + (size_t)tid*256;
  const int u4 = tid >> 2, q4 = tid & 3;

  for (int t=0; t<128; t++){
    const int y = tgt_g[t];
    const float gy = gtok[(size_t)y*1024 + tid];

    // P1: gate row tid = gy + Wio@o + Whh@h   (weights streamed from L2)
    { float a = gy;
      #pragma unroll 4
      for (int c=0; c<32; c++) a += dot8(ld8f(wio + c*8), sO + c*8);
      #pragma unroll 4
      for (int c=0; c<32; c++) a += dot8(ld8f(whh + c*8), sH + c*8);
      sG[tid] = a;
    }
    __syncthreads();                                   // B1

    // P2: LSTM pointwise (gate order i,f,g,o)
    if (tid < 256){
      float ig = sG[tid], fg = sG[256+tid], gg = sG[512+tid], og = sG[768+tid];
      float cn = sigm(fg)*sC[tid] + sigm(ig)*tanh_f(gg);
      sC[tid] = cn;
      sH[tid] = sigm(og)*tanh_f(cn);
    }
    __syncthreads();                                   // B2

    // P3: hW2[d] = W2[d]@h  (d=u4, quarter q4; shfl reduce)
    { float a = 0.f;
      const float* w2r = W2 + (size_t)u4*256 + q4*64;
      const float* x = sH + q4*64;
      #pragma unroll
      for (int c=0; c<8; c++) a += dot8(ld8f(w2r + c*8), x + c*8);
      a += __shfl_xor(a,1); a += __shfl_xor(a,2);
      if (q4 == 0) sHw2[u4] = a;
    }
    __syncthreads();                                   // B3

    // P4: scores l=u4 (quarter q4): sc = sum tanh(enc+hW2)*beta; e=exp(sc); se
    { float sc = 0.f;
      const float* er = ENCg + (size_t)u4*256 + q4*64;
      const float* hw = sHw2 + q4*64;
      const float* bt = sBeta + q4*64;
      #pragma unroll 2
      for (int c=0; c<8; c++){
        F8 ev = ld8f(er + c*8);
        #pragma unroll
        for (int i=0; i<8; i++) sc += tanh_f(ev.v[i] + hw[c*8+i]) * bt[c*8+i];
      }
      sc += __shfl_xor(sc,1); sc += __shfl_xor(sc,2);
      float e = 0.f;
      if (q4 == 0){ e = __expf(sc); sE[u4] = e; }      // |sc| <= sum|beta| ~1.3
      float es = (q4 == 0) ? e : 0.f;                   // wave-sum of 16 e's
      es += __shfl_xor(es,1);  es += __shfl_xor(es,2);  es += __shfl_xor(es,4);
      es += __shfl_xor(es,8);  es += __shfl_xor(es,16); es += __shfl_xor(es,32);
      if ((tid & 63) == 0) sScal[tid >> 6] = es;        // 16 wave partials
    }
    __syncthreads();                                   // B4
    if (tid == 0){
      float se = 0.f;
      #pragma unroll
      for (int i=0; i<16; i++) se += sScal[i];
      sScal[16] = se;
    }

    // P5: ctx[d] = (sum_l e_l * imgs[g][l][d]) / se   (d=u4, l-quarter q4)
    float csum;
    { float a = 0.f;
      const float* eb = sE + q4*64;
      const float* ib = imgs + ((size_t)g*256 + q4*64)*256 + u4;
      #pragma unroll 4
      for (int i=0; i<64; i++) a += eb[i] * ib[(size_t)i*256];
      a += __shfl_xor(a,1); a += __shfl_xor(a,2);
      csum = a;
    }
    __syncthreads();                                   // B5 (sScal[16] visible)
    if (q4 == 0) sCtx[u4] = csum / sScal[16];
    __syncthreads();                                   // B6

    // P6: o[u] = tanh(W3[u] @ [h; ctx])  (u=u4, 128-elem quarter q4)
    { float a = 0.f;
      const float* w3r = W3 + (size_t)u4*512 + q4*128;
      const float* x = (q4 < 2) ? (sH + q4*128) : (sCtx + (q4-2)*128);
      #pragma unroll 2
      for (int c=0; c<16; c++) a += dot8(ld8f(w3r + c*8), x + c*8);
      a += __shfl_xor(a,1); a += __shfl_xor(a,2);
      if (q4 == 0){
        float o = tanh_f(a);
        sO[u4] = o;
        oLDS[t*260 + u4] = o;
      }
    }
    __syncthreads();                                   // B7 (end of step)
  }

  // ---- epilogue: logits + softmax, 8 lanes per (t), shuffle-only reductions ----
  { const int tt = tid >> 3, qe = tid & 7;
    const int v0 = qe * 22;                            // 7*22=154, last lane 18 rows
    float acc[22];
    #pragma unroll
    for (int i=0; i<22; i++) acc[i] = 0.f;
    for (int kc=0; kc<16; kc++){
      float o16[16];
      { const float4* ob = (const float4*)(oLDS + tt*260 + kc*16);
        #pragma unroll
        for (int k=0; k<4; k++){
          float4 v = ob[k];
          o16[k*4+0]=v.x; o16[k*4+1]=v.y; o16[k*4+2]=v.z; o16[k*4+3]=v.w;
        }
      }
      #pragma unroll
      for (int i=0; i<22; i++){
        if (v0 + i < 172){
          const float* wr = Wout + (size_t)(v0+i)*256 + kc*16;
          F8 w0 = ld8f(wr), w1 = ld8f(wr + 8);
          float a = 0.f;
          #pragma unroll
          for (int k=0; k<8; k++) a += w0.v[k]*o16[k] + w1.v[k]*o16[8+k];
          acc[i] += a;
        }
      }
    }
    float m = -1e30f;
    #pragma unroll
    for (int i=0; i<22; i++) if (v0+i < 172) m = fmaxf(m, acc[i]);
    m = fmaxf(m, __shfl_xor(m,1)); m = fmaxf(m, __shfl_xor(m,2)); m = fmaxf(m, __shfl_xor(m,4));
    float s = 0.f;
    #pragma unroll
    for (int i=0; i<22; i++){
      acc[i] = (v0+i < 172) ? __expf(acc[i] - m) : 0.f;
      s += acc[i];
    }
    s += __shfl_xor(s,1); s += __shfl_xor(s,2); s += __shfl_xor(s,4);
    const float inv = 1.0f / s;
    #pragma unroll
    for (int i=0; i<22; i++)
      if (v0+i < 172) out[((size_t)g*128 + tt)*172 + v0 + i] = acc[i]*inv;
  }
}

extern "C" void kernel_launch(void* const* d_in, const int* in_sizes, int n_in,
                              void* d_out, int out_size, void* d_ws, size_t ws_size,
                              hipStream_t stream) {
  (void)in_sizes; (void)n_in; (void)out_size; (void)ws_size;
  char* ws = (char*)d_ws;
  k_all<<<16, 1024, 0, stream>>>(
      (const float*)d_in[0],  (const int*)d_in[1],   (const float*)d_in[2],
      (const float*)d_in[3],  (const float*)d_in[4],  (const float*)d_in[5],
      (const float*)d_in[6],  (const float*)d_in[7],  (const float*)d_in[8],
      (const float*)d_in[9],  (const float*)d_in[10], (const float*)d_in[11],
      (const float*)d_in[12], (const float*)d_in[13], (const float*)d_in[14],
      (const float*)d_in[15], (const float*)d_in[16], (const float*)d_in[17],
      ws, (float*)d_out);
}

// Round 9
// 4529.353 us; speedup vs baseline: 3.0695x; 3.0695x over previous
//
#include <hip/hip_runtime.h>

typedef unsigned int u32;

// sizes: B=16, L=256, D=256, H=256, E=256, V=172, T=128   (all inputs f32, output f32)
// R9 = R5 (8 WGs x 512 thr per group) with the WORKSPACE OFFSET BUG FIXED:
// R5 gave pQH only 128KB but [2][16][8][256]f32 = 256KB -> par=1 writes corrupted pCTX.
// Structure: grid 128. g=bid&15, w=bid>>4 (0..7). WG (g,w) owns 32 LSTM units and
// 32 l-rows. Weights register-resident (wior64+whhr64+w2p64+w3h16 = 208 VGPR < 256).
// Protocol = R2's proven transport: untagged f32 + per-WG monotone flag, relaxed
// agent-scope atomics; in-loop publish = vmcnt drain + relaxed flag store; one TRUE
// release at seq 1 flushes plain-stored gtok. stH/pQH parity dbuf, pCTX/pSE single
// (WAR-safe via flag chain). hpart (W_hh@h) in P2's shadow.
// Rationale: hop cost ~4us = RTT ~2us + straggler skew at 16-way max; 8-WG convoy
// halves the skew term and halves P3 reduce fan-in.

// workspace layout (bytes) -- FIXED
#define OFF_BAR   0ull          // u32 [16][8][16]  flag(g,w) at g*512B + w*64B
#define OFF_PSE   16384ull      // f32 [16][8]           partial exp-sums      (512B)
#define OFF_STH   32768ull      // f32 [2][16][256]      ping-pong h           (32KB)
#define OFF_PQH   65536ull      // f32 [2][16][8][256]   partial W3h@h         (256KB)
#define OFF_PCTX  327680ull     // f32 [16][8][256]      partial e-wt Pimg     (128KB)
#define OFF_OALL  458752ull     // f32 [128][16][256]    o_t per step          (2MB)
#define OFF_GTOK  2555904ull    // f32 [172][1024]       emb-gates + biases    (688KB)

__device__ __forceinline__ float sigm(float x){ return 1.0f/(1.0f+__expf(-x)); }
__device__ __forceinline__ float tanh_f(float x){ return 1.0f - 2.0f/(1.0f+__expf(2.0f*x)); }

__device__ __forceinline__ float blo(u32 q){ u32 x = q<<16; float f; __builtin_memcpy(&f,&x,4); return f; }
__device__ __forceinline__ float bhi(u32 q){ u32 x = q & 0xffff0000u; float f; __builtin_memcpy(&f,&x,4); return f; }
__device__ __forceinline__ u32 f2bu(float f){ u32 x; __builtin_memcpy(&x,&f,4); x = x + 0x7fffu + ((x>>16)&1u); return x>>16; }

struct F8 { float v[8]; };
__device__ __forceinline__ F8 ld8f(const float* q){
  F8 r; float4 a = *(const float4*)q; float4 b = *(const float4*)(q+4);
  r.v[0]=a.x;r.v[1]=a.y;r.v[2]=a.z;r.v[3]=a.w;r.v[4]=b.x;r.v[5]=b.y;r.v[6]=b.z;r.v[7]=b.w;
  return r;
}
__device__ __forceinline__ float dot8(const F8& w, const float* x){
  float4 a = *(const float4*)x; float4 b = *(const float4*)(x+4);
  return w.v[0]*a.x + w.v[1]*a.y + w.v[2]*a.z + w.v[3]*a.w
       + w.v[4]*b.x + w.v[5]*b.y + w.v[6]*b.z + w.v[7]*b.w;
}
__device__ __forceinline__ float dot8r(const float* wr, const float* x){
  float4 a = *(const float4*)x; float4 b = *(const float4*)(x+4);
  return wr[0]*a.x + wr[1]*a.y + wr[2]*a.z + wr[3]*a.w
       + wr[4]*b.x + wr[5]*b.y + wr[6]*b.z + wr[7]*b.w;
}

// agent-scope (MALL-direct) 4B ops for all cross-WG data
__device__ __forceinline__ float cohload(const float* p){
  u32 x = __hip_atomic_load((const u32*)p, __ATOMIC_RELAXED, __HIP_MEMORY_SCOPE_AGENT);
  float f; __builtin_memcpy(&f,&x,4); return f;
}
__device__ __forceinline__ void cohstore(float* p, float v){
  u32 x; __builtin_memcpy(&x,&v,4);
  __hip_atomic_store((u32*)p, x, __ATOMIC_RELAXED, __HIP_MEMORY_SCOPE_AGENT);
}

// consumer side: lanes 0..7 poll the 8 producer flags in parallel (relaxed loads)
__device__ __forceinline__ void wait_flags(u32* gf, u32 seq){
  if (threadIdx.x < 8){
    while (__hip_atomic_load(gf + threadIdx.x*16, __ATOMIC_RELAXED, __HIP_MEMORY_SCOPE_AGENT) < seq){
      __builtin_amdgcn_s_sleep(1);
    }
  }
  __syncthreads();
}
// setup-only: true release (wbl2 -> flushes the PLAIN gtok stores)
__device__ __forceinline__ void publish_flag(u32* myf, u32 seq){
  __hip_atomic_store(myf, seq, __ATOMIC_RELEASE, __HIP_MEMORY_SCOPE_AGENT);
}
// in-loop: prior cross-WG data all went through sc1 atomics; vmcnt drain suffices
__device__ __forceinline__ void publish_flag_fast(u32* myf, u32 seq){
  asm volatile("s_waitcnt vmcnt(0)" ::: "memory");
  __hip_atomic_store(myf, seq, __ATOMIC_RELAXED, __HIP_MEMORY_SCOPE_AGENT);
}

// ---------------- K0: zero flags (ws poisoned 0xAA pre-launch) ----------------
extern "C" __global__ __launch_bounds__(256)
void k_init(char* __restrict__ ws){
  u32* bar = (u32*)(ws + OFF_BAR);
  const int gt = blockIdx.x*256 + threadIdx.x;
  if (gt < 2048) bar[gt] = 0u;
}

// ---------------- K1: parallel recurrence, 16 groups x 8 WGs x 512 thr ----------------
extern "C" __global__ __launch_bounds__(512, 2)
void k_main(const float* __restrict__ imgs, const int* __restrict__ tgt,
            const float* __restrict__ emb,  const float* __restrict__ W_ih,
            const float* __restrict__ W_hh, const float* __restrict__ b_ih,
            const float* __restrict__ b_hh, const float* __restrict__ W1,
            const float* __restrict__ W2,   const float* __restrict__ W3,
            const float* __restrict__ beta, const float* __restrict__ whW,
            const float* __restrict__ whb,  const float* __restrict__ wcW,
            const float* __restrict__ wcb,  const float* __restrict__ woW,
            const float* __restrict__ wob,  char* __restrict__ ws)
{
  const int tid = threadIdx.x, bid = blockIdx.x;
  const int g = bid & 15, w = bid >> 4, u0 = w*32;

  u32* gf   = (u32*)(ws + OFF_BAR) + g*128;      // group's 8 flags, 64B apart
  u32* myf  = gf + w*16;
  float* stH  = (float*)(ws + OFF_STH);
  float* pQH  = (float*)(ws + OFF_PQH);
  float* pCTX = (float*)(ws + OFF_PCTX);
  float* pSE  = (float*)(ws + OFF_PSE);
  float* oAll = (float*)(ws + OFF_OALL);
  float* gtok = (float*)(ws + OFF_GTOK);

  __shared__ __align__(16) float sImg[32*256];   // own (b, l-chunk) img rows   32KB
  __shared__ __align__(16) float sEnc[32*256];   // own enc_proj rows            32KB
  __shared__ __align__(16) float sPimg[32*256];  // own W3c@img rows             32KB
  __shared__ __align__(16) float sPool[256];     // setup scratch (emb / mean)
  __shared__ __align__(16) float sHprev[256];    // full h_t (local)
  __shared__ __align__(16) float sO[256];        // full o_{t-1} (local)
  __shared__ __align__(16) float sHw2[256];
  __shared__ float sBeta[256];
  __shared__ float sG[128];
  __shared__ float sHown[32];
  __shared__ float sC[32];
  __shared__ float sE[32];
  __shared__ float sE2[8];

  if (tid < 256) sBeta[tid] = beta[tid];

  // ---- phase A: gtok[v][j] = W_ih[j][0:256]@emb[v] + b_ih[j] + b_hh[j] ----
  // 172 tokens x 2 half-row-blocks = 344 tasks over 128 WGs x 3 rounds
  for (int r=0; r<3; r++){
    const int tk = bid + 128*r;
    __syncthreads();
    if (tk < 344){
      const int v = tk>>1, h2 = tk&1;
      if (tid < 256) sPool[tid] = emb[(size_t)v*256 + tid];
      __syncthreads();
      const int j = h2*512 + tid;                  // 512 rows per half
      const float* wr = W_ih + (size_t)j*512;
      float a = 0.f;
      #pragma unroll 8
      for (int c=0; c<32; c++) a += dot8(ld8f(wr + c*8), sPool + c*8);
      gtok[(size_t)v*1024 + j] = a + b_ih[j] + b_hh[j];   // plain; flushed by seq-1 release
    } else {
      __syncthreads();
    }
  }
  __syncthreads();

  // ---- setup: stage img chunk (32 rows); enc_proj (W1) and Pimg (W3c) rows ----
  { const size_t r0 = (size_t)(g*256 + w*32);
    const int dcol = tid & 255, rh = tid >> 8;     // rh=0/1 -> rows rh*16..+16
    for (int ri=0; ri<16; ri++)
      sImg[(rh*16+ri)*256 + dcol] = imgs[(r0 + rh*16 + ri)*256 + dcol];
    __syncthreads();
    { float acc[16];
      #pragma unroll
      for (int ri=0; ri<16; ri++) acc[ri]=0.f;
      const float* w1r = W1 + (size_t)dcol*256;
      for (int c=0; c<32; c++){
        F8 wv = ld8f(w1r + c*8);
        #pragma unroll
        for (int ri=0; ri<16; ri++) acc[ri] += dot8(wv, sImg + (rh*16+ri)*256 + c*8);
      }
      for (int ri=0; ri<16; ri++) sEnc[(rh*16+ri)*256 + dcol] = acc[ri];
    }
    { float acc[16];
      #pragma unroll
      for (int ri=0; ri<16; ri++) acc[ri]=0.f;
      const float* w3cr = W3 + (size_t)dcol*512 + 256;   // ctx-half of W3 row dcol
      for (int c=0; c<32; c++){
        F8 wv = ld8f(w3cr + c*8);
        #pragma unroll
        for (int ri=0; ri<16; ri++) acc[ri] += dot8(wv, sImg + (rh*16+ri)*256 + c*8);
      }
      for (int ri=0; ri<16; ri++) sPimg[(rh*16+ri)*256 + dcol] = acc[ri];
    }
  }
  __syncthreads();

  // ---- init states: mean_enc; FULL h0/o0 locally; own c0 ----
  { const int d = tid>>1, lh = tid&1;
    float m = 0.f;
    for (int l=lh*128; l<lh*128+128; l++) m += imgs[((size_t)g*256 + l)*256 + d];
    m += __shfl_xor(m, 1);
    if (lh == 0) sPool[d] = m * (1.0f/256.0f);
  }
  __syncthreads();
  { const int u = tid>>1, ch = tid&1;
    const float* whr = whW + (size_t)u*256 + ch*128;
    const float* wor = woW + (size_t)u*256 + ch*128;
    float ah=0.f, ao=0.f;
    for (int c=0; c<16; c++){
      ah += dot8(ld8f(whr + c*8), sPool + ch*128 + c*8);
      ao += dot8(ld8f(wor + c*8), sPool + ch*128 + c*8);
    }
    ah += __shfl_xor(ah,1); ao += __shfl_xor(ao,1);
    if (ch == 0){
      sHprev[u] = tanhf(ah + whb[u]);
      sO[u]     = tanhf(ao + wob[u]);
    }
  }
  { const int ul = tid>>4, sub = tid&15;            // ul 0..31
    const int u = u0 + ul;
    float ac=0.f;
    #pragma unroll
    for (int c=0; c<2; c++)
      ac += dot8(ld8f(wcW + (size_t)u*256 + sub*16 + c*8), sPool + sub*16 + c*8);
    ac += __shfl_xor(ac,1); ac += __shfl_xor(ac,2); ac += __shfl_xor(ac,4); ac += __shfl_xor(ac,8);
    if (sub == 0) sC[ul] = tanhf(ac + wcb[u]);
  }

  // ---- per-thread loop constants; weight slices in registers ----
  const int rl = tid>>2, p = tid&3;            // 128 gate-rows x 4 partial lanes
  const int ul_g = rl & 31, gate = rl >> 5;
  const int grow = gate*256 + u0 + ul_g;       // gate row in [4H], order i,f,g,o
  float wior[64], whhr[64];
  { const float* wio = W_ih + (size_t)grow*512 + 256 + p*64;
    const float* whh = W_hh + (size_t)grow*256 +       p*64;
    #pragma unroll
    for (int c=0; c<8; c++){
      F8 a = ld8f(wio + c*8);
      F8 b = ld8f(whh + c*8);
      #pragma unroll
      for (int i=0; i<8; i++){ wior[c*8+i] = a.v[i]; whhr[c*8+i] = b.v[i]; }
    }
  }
  // W2 row d=tid>>1, col-half ch=tid&1, packed bf16 pairs (64 VGPRs)
  const int d2 = tid>>1, ch2 = tid&1;
  u32 w2p[64];
  { const float* w2r = W2 + (size_t)d2*256 + ch2*128;
    #pragma unroll
    for (int c=0; c<64; c++)
      w2p[c] = f2bu(w2r[2*c]) | (f2bu(w2r[2*c+1]) << 16);
  }
  // W3h slice: output row uq=tid>>1, k-half kh=tid&1 over own 32 units (16 VGPRs)
  const int uq = tid>>1, kh = tid&1;
  float w3h[16];
  { F8 a = ld8f(W3 + (size_t)uq*512 + u0 + kh*16);
    F8 b = ld8f(W3 + (size_t)uq*512 + u0 + kh*16 + 8);
    #pragma unroll
    for (int i=0; i<8; i++){ w3h[i] = a.v[i]; w3h[8+i] = b.v[i]; }
  }
  const int* tgt_g = tgt + g*128;
  const float* gtok_row = gtok + grow;

  __syncthreads();                       // drain all waves' init stores (gtok)
  if (tid == 0) publish_flag(myf, 1u);   // TRUE release: wbl2 flushes dirty gtok lines
  wait_flags(gf, 1u);                    // gtok ready

  // hpart = W_hh slice @ h_0 (pre-loop; thereafter computed in P2's hop-shadow)
  float hpart = 0.f;
  { const float* xh = sHprev + p*64;
    #pragma unroll
    for (int c=0; c<8; c++) hpart += dot8r(whhr + c*8, xh + c*8);
  }

  for (int t=0; t<128; t++){
    const int par = t & 1;
    const int y = tgt_g[t];
    const float gyv = gtok_row[(size_t)y*1024];

    // ---- P1 (no wait): gates = hpart + W_ih_o@o; pointwise; publish h (32 units) ----
    { float acc = hpart;
      const float* xo = sO + p*64;
      #pragma unroll
      for (int c=0; c<8; c++) acc += dot8r(wior + c*8, xo + c*8);
      acc += __shfl_xor(acc, 1); acc += __shfl_xor(acc, 2);
      if (p == 0) sG[rl] = acc + gyv;
    }
    __syncthreads();
    if (tid < 32){
      float ig = sG[tid], fg = sG[32+tid], gg = sG[64+tid], og = sG[96+tid];
      float cn = sigm(fg)*sC[tid] + sigm(ig)*tanh_f(gg);
      float hn = sigm(og)*tanh_f(cn);
      sC[tid] = cn;
      sHown[tid] = hn;
      cohstore(stH + par*4096 + g*256 + u0 + tid, hn);   // all stores in wave 0
      if (tid == 0) publish_flag_fast(myf, 2u*t + 2u);    // same wave: vmcnt covers them
    }
    __syncthreads();
    // Qh partial (off the critical path; parity slot): uq over 256, kh halves own 32
    { float qh = 0.f;
      #pragma unroll
      for (int i=0; i<16; i++) qh += w3h[i] * sHown[kh*16 + i];
      qh += __shfl_xor(qh, 1);
      if (kh == 0) cohstore(pQH + ((size_t)(par*16 + g)*8 + w)*256 + uq, qh);
    }

    // ---- P2: wait h; hW2 (reg W2); scores own 32 l's; publish pv/se partials ----
    wait_flags(gf, 2u*t + 2u);
    if (tid < 256) sHprev[tid] = cohload(stH + par*4096 + g*256 + tid);
    __syncthreads();
    { float a = 0.f;
      const float* hb = sHprev + ch2*128;
      #pragma unroll
      for (int c=0; c<64; c++){
        u32 q = w2p[c];
        a += blo(q)*hb[2*c] + bhi(q)*hb[2*c+1];
      }
      a += __shfl_xor(a, 1);
      if (ch2 == 0) sHw2[d2] = a;
    }
    __syncthreads();
    { const int li = tid>>4, sub = tid&15;            // li 0..31
      const float* ep = sEnc + li*256;
      float sc = 0.f;
      #pragma unroll
      for (int i=0; i<16; i++){ int d = i*16 + sub; sc += tanh_f(ep[d] + sHw2[d]) * sBeta[d]; }
      sc += __shfl_xor(sc,1); sc += __shfl_xor(sc,2); sc += __shfl_xor(sc,4); sc += __shfl_xor(sc,8);
      if (sub == 0) sE[li] = __expf(sc);   // |sc| <= sum|beta| ~ 1.3, no max-sub needed
    }
    __syncthreads();
    { float pv = 0.f;
      const int lh = kh;                               // pairing tid = uq*2+kh
      #pragma unroll
      for (int li2=0; li2<16; li2++) pv += sE[lh*16 + li2] * sPimg[(lh*16 + li2)*256 + uq];
      pv += __shfl_xor(pv, 1);
      if (kh == 0) cohstore(pCTX + ((size_t)g*8 + w)*256 + uq, pv);
    }
    if (tid == 0){
      float se = 0.f;
      #pragma unroll
      for (int j=0; j<32; j++) se += sE[j];
      cohstore(pSE + g*8 + w, se);
    }
    // hpart for NEXT step's gates, in the hop-shadow (uses fresh h_t)
    { float hp2 = 0.f;
      const float* xh = sHprev + p*64;
      #pragma unroll
      for (int c=0; c<8; c++) hp2 += dot8r(whhr + c*8, xh + c*8);
      hpart = hp2;
    }
    __syncthreads();                               // drain all waves' pCTX/pQH stores
    if (tid == 0) publish_flag_fast(myf, 2u*t + 3u);

    // ---- P3 (LOCAL): reduce 8 partials; full o_t = tanh(Qh + pv/se) ----
    wait_flags(gf, 2u*t + 3u);
    if (tid < 8) sE2[tid] = cohload(pSE + g*8 + tid);
    float qh = 0.f, pvs = 0.f;
    { const float* qb = pQH  + (size_t)(par*16 + g)*2048 + uq;
      const float* cb = pCTX + (size_t)g*2048 + uq;
      #pragma unroll
      for (int j=0; j<4; j++){
        qh  += cohload(qb + (kh*4 + j)*256);
        pvs += cohload(cb + (kh*4 + j)*256);
      }
      qh  += __shfl_xor(qh, 1);
      pvs += __shfl_xor(pvs, 1);
    }
    __syncthreads();                       // sE2 ready
    { float se = 0.f;
      #pragma unroll
      for (int j=0; j<8; j++) se += sE2[j];
      float o = tanh_f(qh + pvs/se);
      if (kh == 0){
        sO[uq] = o;
        if ((uq>>5) == w) oAll[((size_t)t*16 + g)*256 + uq] = o;  // plain store
      }
    }
    __syncthreads();                       // sO ready for next P1
  }
}

// ---------------- K2: logits + softmax, one (b,t) per WG; f32 output ----------------
extern "C" __global__ __launch_bounds__(256)
void k_logits(const float* __restrict__ Wout, char* __restrict__ ws, float* __restrict__ out){
  __shared__ __align__(16) float sO_[256];
  __shared__ __align__(16) float sRed[256];
  const int tid = threadIdx.x, q = blockIdx.x;
  const int b = q >> 7, t = q & 127;
  const float* oAll = (const float*)(ws + OFF_OALL);
  sO_[tid] = oAll[((size_t)t*16 + b)*256 + tid];
  __syncthreads();
  float lg = 0.f;
  if (tid < 172){
    const float* wr = Wout + (size_t)tid*256;
    #pragma unroll 8
    for (int c=0; c<32; c++) lg += dot8(ld8f(wr + c*8), sO_ + c*8);
  }
  sRed[tid] = (tid < 172) ? lg : -1e30f;
  __syncthreads();
  for (int s2=128; s2>0; s2>>=1){ if (tid < s2) sRed[tid] = fmaxf(sRed[tid], sRed[tid+s2]); __syncthreads(); }
  const float mx = sRed[0];
  __syncthreads();
  const float ev = (tid < 172) ? __expf(lg - mx) : 0.f;
  sRed[tid] = ev;
  __syncthreads();
  for (int s2=128; s2>0; s2>>=1){ if (tid < s2) sRed[tid] += sRed[tid+s2]; __syncthreads(); }
  const float inv = 1.0f / sRed[0];
  if (tid < 172) out[((size_t)b*128 + t)*172 + tid] = ev * inv;
}

extern "C" void kernel_launch(void* const* d_in, const int* in_sizes, int n_in,
                              void* d_out, int out_size, void* d_ws, size_t ws_size,
                              hipStream_t stream) {
  (void)in_sizes; (void)n_in; (void)out_size; (void)ws_size;
  char* ws = (char*)d_ws;
  k_init<<<8, 256, 0, stream>>>(ws);
  k_main<<<128, 512, 0, stream>>>(
      (const float*)d_in[0],  (const int*)d_in[1],  (const float*)d_in[2],
      (const float*)d_in[3],  (const float*)d_in[4], (const float*)d_in[5],
      (const float*)d_in[6],  (const float*)d_in[7], (const float*)d_in[8],
      (const float*)d_in[9],  (const float*)d_in[11], (const float*)d_in[12],
      (const float*)d_in[13], (const float*)d_in[14], (const float*)d_in[15],
      (const float*)d_in[16], (const float*)d_in[17], ws);
  k_logits<<<2048, 256, 0, stream>>>((const float*)d_in[10], ws, (float*)d_out);
}

// Round 10
// 4468.509 us; speedup vs baseline: 3.1113x; 1.0136x over previous
//
#include <hip/hip_runtime.h>

typedef unsigned int u32;

// sizes: B=16, L=256, D=256, H=256, E=256, V=172, T=128   (all inputs f32, output f32)
// R10 = R9 with ONE change: __launch_bounds__(512, 1) instead of (512, 2).
// R9's (512,2) capped VGPRs at 128 < the ~208 named weight regs -> full spill to
// scratch (VGPR_Count=128, FETCH 1.5GB, 4.4ms). An 8-wave block is hardware-bound to
// <=2 waves/SIMD anyway, so (512,1) lets the backend allocate the true max 256 VGPRs.
// Structure: grid 128. g=bid&15, w=bid>>4 (0..7). WG (g,w) owns 32 LSTM units and
// 32 l-rows. Protocol = R2's proven transport (flags + vmcnt-drain publish, one true
// release for gtok). stH/pQH parity dbuf, pCTX/pSE single. hpart in P2's shadow.

// workspace layout (bytes)
#define OFF_BAR   0ull          // u32 [16][8][16]  flag(g,w) at g*512B + w*64B
#define OFF_PSE   16384ull      // f32 [16][8]           partial exp-sums      (512B)
#define OFF_STH   32768ull      // f32 [2][16][256]      ping-pong h           (32KB)
#define OFF_PQH   65536ull      // f32 [2][16][8][256]   partial W3h@h         (256KB)
#define OFF_PCTX  327680ull     // f32 [16][8][256]      partial e-wt Pimg     (128KB)
#define OFF_OALL  458752ull     // f32 [128][16][256]    o_t per step          (2MB)
#define OFF_GTOK  2555904ull    // f32 [172][1024]       emb-gates + biases    (688KB)

__device__ __forceinline__ float sigm(float x){ return 1.0f/(1.0f+__expf(-x)); }
__device__ __forceinline__ float tanh_f(float x){ return 1.0f - 2.0f/(1.0f+__expf(2.0f*x)); }

__device__ __forceinline__ float blo(u32 q){ u32 x = q<<16; float f; __builtin_memcpy(&f,&x,4); return f; }
__device__ __forceinline__ float bhi(u32 q){ u32 x = q & 0xffff0000u; float f; __builtin_memcpy(&f,&x,4); return f; }
__device__ __forceinline__ u32 f2bu(float f){ u32 x; __builtin_memcpy(&x,&f,4); x = x + 0x7fffu + ((x>>16)&1u); return x>>16; }

struct F8 { float v[8]; };
__device__ __forceinline__ F8 ld8f(const float* q){
  F8 r; float4 a = *(const float4*)q; float4 b = *(const float4*)(q+4);
  r.v[0]=a.x;r.v[1]=a.y;r.v[2]=a.z;r.v[3]=a.w;r.v[4]=b.x;r.v[5]=b.y;r.v[6]=b.z;r.v[7]=b.w;
  return r;
}
__device__ __forceinline__ float dot8(const F8& w, const float* x){
  float4 a = *(const float4*)x; float4 b = *(const float4*)(x+4);
  return w.v[0]*a.x + w.v[1]*a.y + w.v[2]*a.z + w.v[3]*a.w
       + w.v[4]*b.x + w.v[5]*b.y + w.v[6]*b.z + w.v[7]*b.w;
}
__device__ __forceinline__ float dot8r(const float* wr, const float* x){
  float4 a = *(const float4*)x; float4 b = *(const float4*)(x+4);
  return wr[0]*a.x + wr[1]*a.y + wr[2]*a.z + wr[3]*a.w
       + wr[4]*b.x + wr[5]*b.y + wr[6]*b.z + wr[7]*b.w;
}

// agent-scope (MALL-direct) 4B ops for all cross-WG data
__device__ __forceinline__ float cohload(const float* p){
  u32 x = __hip_atomic_load((const u32*)p, __ATOMIC_RELAXED, __HIP_MEMORY_SCOPE_AGENT);
  float f; __builtin_memcpy(&f,&x,4); return f;
}
__device__ __forceinline__ void cohstore(float* p, float v){
  u32 x; __builtin_memcpy(&x,&v,4);
  __hip_atomic_store((u32*)p, x, __ATOMIC_RELAXED, __HIP_MEMORY_SCOPE_AGENT);
}

// consumer side: lanes 0..7 poll the 8 producer flags in parallel (relaxed loads)
__device__ __forceinline__ void wait_flags(u32* gf, u32 seq){
  if (threadIdx.x < 8){
    while (__hip_atomic_load(gf + threadIdx.x*16, __ATOMIC_RELAXED, __HIP_MEMORY_SCOPE_AGENT) < seq){
      __builtin_amdgcn_s_sleep(1);
    }
  }
  __syncthreads();
}
// setup-only: true release (wbl2 -> flushes the PLAIN gtok stores)
__device__ __forceinline__ void publish_flag(u32* myf, u32 seq){
  __hip_atomic_store(myf, seq, __ATOMIC_RELEASE, __HIP_MEMORY_SCOPE_AGENT);
}
// in-loop: prior cross-WG data all went through sc1 atomics; vmcnt drain suffices
__device__ __forceinline__ void publish_flag_fast(u32* myf, u32 seq){
  asm volatile("s_waitcnt vmcnt(0)" ::: "memory");
  __hip_atomic_store(myf, seq, __ATOMIC_RELAXED, __HIP_MEMORY_SCOPE_AGENT);
}

// ---------------- K0: zero flags (ws poisoned 0xAA pre-launch) ----------------
extern "C" __global__ __launch_bounds__(256)
void k_init(char* __restrict__ ws){
  u32* bar = (u32*)(ws + OFF_BAR);
  const int gt = blockIdx.x*256 + threadIdx.x;
  if (gt < 2048) bar[gt] = 0u;
}

// ---------------- K1: parallel recurrence, 16 groups x 8 WGs x 512 thr ----------------
extern "C" __global__ __launch_bounds__(512, 1)
void k_main(const float* __restrict__ imgs, const int* __restrict__ tgt,
            const float* __restrict__ emb,  const float* __restrict__ W_ih,
            const float* __restrict__ W_hh, const float* __restrict__ b_ih,
            const float* __restrict__ b_hh, const float* __restrict__ W1,
            const float* __restrict__ W2,   const float* __restrict__ W3,
            const float* __restrict__ beta, const float* __restrict__ whW,
            const float* __restrict__ whb,  const float* __restrict__ wcW,
            const float* __restrict__ wcb,  const float* __restrict__ woW,
            const float* __restrict__ wob,  char* __restrict__ ws)
{
  const int tid = threadIdx.x, bid = blockIdx.x;
  const int g = bid & 15, w = bid >> 4, u0 = w*32;

  u32* gf   = (u32*)(ws + OFF_BAR) + g*128;      // group's 8 flags, 64B apart
  u32* myf  = gf + w*16;
  float* stH  = (float*)(ws + OFF_STH);
  float* pQH  = (float*)(ws + OFF_PQH);
  float* pCTX = (float*)(ws + OFF_PCTX);
  float* pSE  = (float*)(ws + OFF_PSE);
  float* oAll = (float*)(ws + OFF_OALL);
  float* gtok = (float*)(ws + OFF_GTOK);

  __shared__ __align__(16) float sImg[32*256];   // own (b, l-chunk) img rows   32KB
  __shared__ __align__(16) float sEnc[32*256];   // own enc_proj rows            32KB
  __shared__ __align__(16) float sPimg[32*256];  // own W3c@img rows             32KB
  __shared__ __align__(16) float sPool[256];     // setup scratch (emb / mean)
  __shared__ __align__(16) float sHprev[256];    // full h_t (local)
  __shared__ __align__(16) float sO[256];        // full o_{t-1} (local)
  __shared__ __align__(16) float sHw2[256];
  __shared__ float sBeta[256];
  __shared__ float sG[128];
  __shared__ float sHown[32];
  __shared__ float sC[32];
  __shared__ float sE[32];
  __shared__ float sE2[8];

  if (tid < 256) sBeta[tid] = beta[tid];

  // ---- phase A: gtok[v][j] = W_ih[j][0:256]@emb[v] + b_ih[j] + b_hh[j] ----
  // 172 tokens x 2 half-row-blocks = 344 tasks over 128 WGs x 3 rounds
  for (int r=0; r<3; r++){
    const int tk = bid + 128*r;
    __syncthreads();
    if (tk < 344){
      const int v = tk>>1, h2 = tk&1;
      if (tid < 256) sPool[tid] = emb[(size_t)v*256 + tid];
      __syncthreads();
      const int j = h2*512 + tid;                  // 512 rows per half
      const float* wr = W_ih + (size_t)j*512;
      float a = 0.f;
      #pragma unroll 8
      for (int c=0; c<32; c++) a += dot8(ld8f(wr + c*8), sPool + c*8);
      gtok[(size_t)v*1024 + j] = a + b_ih[j] + b_hh[j];   // plain; flushed by seq-1 release
    } else {
      __syncthreads();
    }
  }
  __syncthreads();

  // ---- setup: stage img chunk (32 rows); enc_proj (W1) and Pimg (W3c) rows ----
  { const size_t r0 = (size_t)(g*256 + w*32);
    const int dcol = tid & 255, rh = tid >> 8;     // rh=0/1 -> rows rh*16..+16
    for (int ri=0; ri<16; ri++)
      sImg[(rh*16+ri)*256 + dcol] = imgs[(r0 + rh*16 + ri)*256 + dcol];
    __syncthreads();
    { float acc[16];
      #pragma unroll
      for (int ri=0; ri<16; ri++) acc[ri]=0.f;
      const float* w1r = W1 + (size_t)dcol*256;
      for (int c=0; c<32; c++){
        F8 wv = ld8f(w1r + c*8);
        #pragma unroll
        for (int ri=0; ri<16; ri++) acc[ri] += dot8(wv, sImg + (rh*16+ri)*256 + c*8);
      }
      for (int ri=0; ri<16; ri++) sEnc[(rh*16+ri)*256 + dcol] = acc[ri];
    }
    { float acc[16];
      #pragma unroll
      for (int ri=0; ri<16; ri++) acc[ri]=0.f;
      const float* w3cr = W3 + (size_t)dcol*512 + 256;   // ctx-half of W3 row dcol
      for (int c=0; c<32; c++){
        F8 wv = ld8f(w3cr + c*8);
        #pragma unroll
        for (int ri=0; ri<16; ri++) acc[ri] += dot8(wv, sImg + (rh*16+ri)*256 + c*8);
      }
      for (int ri=0; ri<16; ri++) sPimg[(rh*16+ri)*256 + dcol] = acc[ri];
    }
  }
  __syncthreads();

  // ---- init states: mean_enc; FULL h0/o0 locally; own c0 ----
  { const int d = tid>>1, lh = tid&1;
    float m = 0.f;
    for (int l=lh*128; l<lh*128+128; l++) m += imgs[((size_t)g*256 + l)*256 + d];
    m += __shfl_xor(m, 1);
    if (lh == 0) sPool[d] = m * (1.0f/256.0f);
  }
  __syncthreads();
  { const int u = tid>>1, ch = tid&1;
    const float* whr = whW + (size_t)u*256 + ch*128;
    const float* wor = woW + (size_t)u*256 + ch*128;
    float ah=0.f, ao=0.f;
    for (int c=0; c<16; c++){
      ah += dot8(ld8f(whr + c*8), sPool + ch*128 + c*8);
      ao += dot8(ld8f(wor + c*8), sPool + ch*128 + c*8);
    }
    ah += __shfl_xor(ah,1); ao += __shfl_xor(ao,1);
    if (ch == 0){
      sHprev[u] = tanhf(ah + whb[u]);
      sO[u]     = tanhf(ao + wob[u]);
    }
  }
  { const int ul = tid>>4, sub = tid&15;            // ul 0..31
    const int u = u0 + ul;
    float ac=0.f;
    #pragma unroll
    for (int c=0; c<2; c++)
      ac += dot8(ld8f(wcW + (size_t)u*256 + sub*16 + c*8), sPool + sub*16 + c*8);
    ac += __shfl_xor(ac,1); ac += __shfl_xor(ac,2); ac += __shfl_xor(ac,4); ac += __shfl_xor(ac,8);
    if (sub == 0) sC[ul] = tanhf(ac + wcb[u]);
  }

  // ---- per-thread loop constants; weight slices in registers ----
  const int rl = tid>>2, p = tid&3;            // 128 gate-rows x 4 partial lanes
  const int ul_g = rl & 31, gate = rl >> 5;
  const int grow = gate*256 + u0 + ul_g;       // gate row in [4H], order i,f,g,o
  float wior[64], whhr[64];
  { const float* wio = W_ih + (size_t)grow*512 + 256 + p*64;
    const float* whh = W_hh + (size_t)grow*256 +       p*64;
    #pragma unroll
    for (int c=0; c<8; c++){
      F8 a = ld8f(wio + c*8);
      F8 b = ld8f(whh + c*8);
      #pragma unroll
      for (int i=0; i<8; i++){ wior[c*8+i] = a.v[i]; whhr[c*8+i] = b.v[i]; }
    }
  }
  // W2 row d=tid>>1, col-half ch=tid&1, packed bf16 pairs (64 VGPRs)
  const int d2 = tid>>1, ch2 = tid&1;
  u32 w2p[64];
  { const float* w2r = W2 + (size_t)d2*256 + ch2*128;
    #pragma unroll
    for (int c=0; c<64; c++)
      w2p[c] = f2bu(w2r[2*c]) | (f2bu(w2r[2*c+1]) << 16);
  }
  // W3h slice: output row uq=tid>>1, k-half kh=tid&1 over own 32 units (16 VGPRs)
  const int uq = tid>>1, kh = tid&1;
  float w3h[16];
  { F8 a = ld8f(W3 + (size_t)uq*512 + u0 + kh*16);
    F8 b = ld8f(W3 + (size_t)uq*512 + u0 + kh*16 + 8);
    #pragma unroll
    for (int i=0; i<8; i++){ w3h[i] = a.v[i]; w3h[8+i] = b.v[i]; }
  }
  const int* tgt_g = tgt + g*128;
  const float* gtok_row = gtok + grow;

  __syncthreads();                       // drain all waves' init stores (gtok)
  if (tid == 0) publish_flag(myf, 1u);   // TRUE release: wbl2 flushes dirty gtok lines
  wait_flags(gf, 1u);                    // gtok ready

  // hpart = W_hh slice @ h_0 (pre-loop; thereafter computed in P2's hop-shadow)
  float hpart = 0.f;
  { const float* xh = sHprev + p*64;
    #pragma unroll
    for (int c=0; c<8; c++) hpart += dot8r(whhr + c*8, xh + c*8);
  }

  for (int t=0; t<128; t++){
    const int par = t & 1;
    const int y = tgt_g[t];
    const float gyv = gtok_row[(size_t)y*1024];

    // ---- P1 (no wait): gates = hpart + W_ih_o@o; pointwise; publish h (32 units) ----
    { float acc = hpart;
      const float* xo = sO + p*64;
      #pragma unroll
      for (int c=0; c<8; c++) acc += dot8r(wior + c*8, xo + c*8);
      acc += __shfl_xor(acc, 1); acc += __shfl_xor(acc, 2);
      if (p == 0) sG[rl] = acc + gyv;
    }
    __syncthreads();
    if (tid < 32){
      float ig = sG[tid], fg = sG[32+tid], gg = sG[64+tid], og = sG[96+tid];
      float cn = sigm(fg)*sC[tid] + sigm(ig)*tanh_f(gg);
      float hn = sigm(og)*tanh_f(cn);
      sC[tid] = cn;
      sHown[tid] = hn;
      cohstore(stH + par*4096 + g*256 + u0 + tid, hn);   // all stores in wave 0
      if (tid == 0) publish_flag_fast(myf, 2u*t + 2u);    // same wave: vmcnt covers them
    }
    __syncthreads();
    // Qh partial (off the critical path; parity slot): uq over 256, kh halves own 32
    { float qh = 0.f;
      #pragma unroll
      for (int i=0; i<16; i++) qh += w3h[i] * sHown[kh*16 + i];
      qh += __shfl_xor(qh, 1);
      if (kh == 0) cohstore(pQH + ((size_t)(par*16 + g)*8 + w)*256 + uq, qh);
    }

    // ---- P2: wait h; hW2 (reg W2); scores own 32 l's; publish pv/se partials ----
    wait_flags(gf, 2u*t + 2u);
    if (tid < 256) sHprev[tid] = cohload(stH + par*4096 + g*256 + tid);
    __syncthreads();
    { float a = 0.f;
      const float* hb = sHprev + ch2*128;
      #pragma unroll
      for (int c=0; c<64; c++){
        u32 q = w2p[c];
        a += blo(q)*hb[2*c] + bhi(q)*hb[2*c+1];
      }
      a += __shfl_xor(a, 1);
      if (ch2 == 0) sHw2[d2] = a;
    }
    __syncthreads();
    { const int li = tid>>4, sub = tid&15;            // li 0..31
      const float* ep = sEnc + li*256;
      float sc = 0.f;
      #pragma unroll
      for (int i=0; i<16; i++){ int d = i*16 + sub; sc += tanh_f(ep[d] + sHw2[d]) * sBeta[d]; }
      sc += __shfl_xor(sc,1); sc += __shfl_xor(sc,2); sc += __shfl_xor(sc,4); sc += __shfl_xor(sc,8);
      if (sub == 0) sE[li] = __expf(sc);   // |sc| <= sum|beta| ~ 1.3, no max-sub needed
    }
    __syncthreads();
    { float pv = 0.f;
      const int lh = kh;                               // pairing tid = uq*2+kh
      #pragma unroll
      for (int li2=0; li2<16; li2++) pv += sE[lh*16 + li2] * sPimg[(lh*16 + li2)*256 + uq];
      pv += __shfl_xor(pv, 1);
      if (kh == 0) cohstore(pCTX + ((size_t)g*8 + w)*256 + uq, pv);
    }
    if (tid == 0){
      float se = 0.f;
      #pragma unroll
      for (int j=0; j<32; j++) se += sE[j];
      cohstore(pSE + g*8 + w, se);
    }
    // hpart for NEXT step's gates, in the hop-shadow (uses fresh h_t)
    { float hp2 = 0.f;
      const float* xh = sHprev + p*64;
      #pragma unroll
      for (int c=0; c<8; c++) hp2 += dot8r(whhr + c*8, xh + c*8);
      hpart = hp2;
    }
    __syncthreads();                               // drain all waves' pCTX/pQH stores
    if (tid == 0) publish_flag_fast(myf, 2u*t + 3u);

    // ---- P3 (LOCAL): reduce 8 partials; full o_t = tanh(Qh + pv/se) ----
    wait_flags(gf, 2u*t + 3u);
    if (tid < 8) sE2[tid] = cohload(pSE + g*8 + tid);
    float qh = 0.f, pvs = 0.f;
    { const float* qb = pQH  + (size_t)(par*16 + g)*2048 + uq;
      const float* cb = pCTX + (size_t)g*2048 + uq;
      #pragma unroll
      for (int j=0; j<4; j++){
        qh  += cohload(qb + (kh*4 + j)*256);
        pvs += cohload(cb + (kh*4 + j)*256);
      }
      qh  += __shfl_xor(qh, 1);
      pvs += __shfl_xor(pvs, 1);
    }
    __syncthreads();                       // sE2 ready
    { float se = 0.f;
      #pragma unroll
      for (int j=0; j<8; j++) se += sE2[j];
      float o = tanh_f(qh + pvs/se);
      if (kh == 0){
        sO[uq] = o;
        if ((uq>>5) == w) oAll[((size_t)t*16 + g)*256 + uq] = o;  // plain store
      }
    }
    __syncthreads();                       // sO ready for next P1
  }
}

// ---------------- K2: logits + softmax, one (b,t) per WG; f32 output ----------------
extern "C" __global__ __launch_bounds__(256)
void k_logits(const float* __restrict__ Wout, char* __restrict__ ws, float* __restrict__ out){
  __shared__ __align__(16) float sO_[256];
  __shared__ __align__(16) float sRed[256];
  const int tid = threadIdx.x, q = blockIdx.x;
  const int b = q >> 7, t = q & 127;
  const float* oAll = (const float*)(ws + OFF_OALL);
  sO_[tid] = oAll[((size_t)t*16 + b)*256 + tid];
  __syncthreads();
  float lg = 0.f;
  if (tid < 172){
    const float* wr = Wout + (size_t)tid*256;
    #pragma unroll 8
    for (int c=0; c<32; c++) lg += dot8(ld8f(wr + c*8), sO_ + c*8);
  }
  sRed[tid] = (tid < 172) ? lg : -1e30f;
  __syncthreads();
  for (int s2=128; s2>0; s2>>=1){ if (tid < s2) sRed[tid] = fmaxf(sRed[tid], sRed[tid+s2]); __syncthreads(); }
  const float mx = sRed[0];
  __syncthreads();
  const float ev = (tid < 172) ? __expf(lg - mx) : 0.f;
  sRed[tid] = ev;
  __syncthreads();
  for (int s2=128; s2>0; s2>>=1){ if (tid < s2) sRed[tid] += sRed[tid+s2]; __syncthreads(); }
  const float inv = 1.0f / sRed[0];
  if (tid < 172) out[((size_t)b*128 + t)*172 + tid] = ev * inv;
}

extern "C" void kernel_launch(void* const* d_in, const int* in_sizes, int n_in,
                              void* d_out, int out_size, void* d_ws, size_t ws_size,
                              hipStream_t stream) {
  (void)in_sizes; (void)n_in; (void)out_size; (void)ws_size;
  char* ws = (char*)d_ws;
  k_init<<<8, 256, 0, stream>>>(ws);
  k_main<<<128, 512, 0, stream>>>(
      (const float*)d_in[0],  (const int*)d_in[1],  (const float*)d_in[2],
      (const float*)d_in[3],  (const float*)d_in[4], (const float*)d_in[5],
      (const float*)d_in[6],  (const float*)d_in[7], (const float*)d_in[8],
      (const float*)d_in[9],  (const float*)d_in[11], (const float*)d_in[12],
      (const float*)d_in[13], (const float*)d_in[14], (const float*)d_in[15],
      (const float*)d_in[16], (const float*)d_in[17], ws);
  k_logits<<<2048, 256, 0, stream>>>((const float*)d_in[10], ws, (float*)d_out);
}